// Round 2
// baseline (565.144 us; speedup 1.0000x reference)
//
#include <hip/hip_runtime.h>

typedef unsigned short u16;
typedef unsigned int   u32;
typedef unsigned char  u8;
typedef __attribute__((ext_vector_type(8))) short bf16x8;
typedef __attribute__((ext_vector_type(4))) float f32x4;

#define B_  4
#define S_  2048
#define D_  1024
#define H_  16
#define DH_ 64
#define M_  (B_*S_)

__device__ __forceinline__ u16 f2bf(float f) {
  u32 u = __builtin_bit_cast(u32, f);
  u32 r = (u + 0x7FFFu + ((u >> 16) & 1u)) >> 16;   // RNE
  return (u16)r;
}

__device__ __forceinline__ void gload_lds16(const void* g, void* l) {
  __builtin_amdgcn_global_load_lds(
      (const __attribute__((address_space(1))) u32*)g,
      (__attribute__((address_space(3))) u32*)l,
      16, 0, 0);
}

// ---------------- prep: X f32 -> bf16 ----------------
__global__ __launch_bounds__(256) void convert_x(const float* __restrict__ x,
                                                 u16* __restrict__ xb) {
  const int i = (blockIdx.x * 256 + threadIdx.x) * 4;   // grid 8192 covers 8388608
  float4 v = *(const float4*)(x + i);
  ushort4 o;
  o.x = f2bf(v.x); o.y = f2bf(v.y); o.z = f2bf(v.z); o.w = f2bf(v.w);
  *(ushort4*)(xb + i) = o;
}

// ---------------- prep: W[k][n] f32 -> Wt[n][k] bf16 ----------------
__global__ __launch_bounds__(256) void transpose_w(
    const float* __restrict__ W0, const float* __restrict__ W1,
    const float* __restrict__ W2, const float* __restrict__ W3,
    u16* __restrict__ T0, u16* __restrict__ T1,
    u16* __restrict__ T2, u16* __restrict__ T3) {
  __shared__ float t[64][65];
  const int z = blockIdx.z;
  const float* W = z == 0 ? W0 : z == 1 ? W1 : z == 2 ? W2 : W3;
  u16* T        = z == 0 ? T0 : z == 1 ? T1 : z == 2 ? T2 : T3;
  const int n0 = blockIdx.x * 64, k0 = blockIdx.y * 64;
  const int c = threadIdx.x & 63, r0 = threadIdx.x >> 6;
#pragma unroll
  for (int i = 0; i < 16; i++)
    t[r0 + i * 4][c] = W[(size_t)(k0 + r0 + i * 4) * 1024 + n0 + c];
  __syncthreads();
#pragma unroll
  for (int i = 0; i < 16; i++)
    T[(size_t)(n0 + r0 + i * 4) * 1024 + k0 + c] = f2bf(t[c][r0 + i * 4]);
}

// ---------------- GEMM: C[8192,1024] = A[8192,1024] @ Bt[1024,1024]^T + bias --------
// mode 0: bf16 out, [b][h][s][dh] layout (Q/K)     (oscale folds 1/sqrt(DH) for Q)
// mode 1: bf16 out, [b][h][dh][s] layout (V transposed)
// mode 2: f32 out, row-major [m][n] (final projection)
__global__ __launch_bounds__(256) void gemm_bt(
    const u16* __restrict__ A, const u16* __restrict__ Bw,
    const float* __restrict__ bias, void* __restrict__ outp,
    int mode, float oscale) {
  __shared__ u16 As[128 * 32];
  __shared__ u16 Bs[128 * 32];
  const int tid = threadIdx.x;
  const int lane = tid & 63, wid = tid >> 6;
  const int wr = wid >> 1, wc = wid & 1;
  const int bm = blockIdx.x, bn = blockIdx.y;
  const int lr = lane & 15, lk8 = (lane >> 4) * 8, lg = (lane >> 4) * 4;

  f32x4 zero = {0.f, 0.f, 0.f, 0.f};
  f32x4 acc[4][4];
#pragma unroll
  for (int i = 0; i < 4; i++)
#pragma unroll
    for (int j = 0; j < 4; j++) acc[i][j] = zero;

  // staging: thread t -> 16B at tile byte offset t*16 (+4096 for second half)
  const int r0 = tid >> 2;            // tile row (of 128), rows are 32 bf16 = 64B
  const int c0 = (tid & 3) * 8;       // elem col within row
  const u16* gA = A + ((size_t)(bm * 128 + r0) << 10) + c0;
  const u16* gB = Bw + ((size_t)(bn * 128 + r0) << 10) + c0;
  u16* lA = &As[tid * 8];
  u16* lB = &Bs[tid * 8];

  for (int kt = 0; kt < 1024; kt += 32) {
    gload_lds16(gA + kt, lA);
    gload_lds16(gA + kt + (64 << 10), lA + 64 * 32);
    gload_lds16(gB + kt, lB);
    gload_lds16(gB + kt + (64 << 10), lB + 64 * 32);
    __syncthreads();

    bf16x8 af[4], bfr[4];
#pragma unroll
    for (int mr = 0; mr < 4; mr++)
      af[mr] = *(const bf16x8*)&As[(wr * 64 + mr * 16 + lr) * 32 + lk8];
#pragma unroll
    for (int nr = 0; nr < 4; nr++)
      bfr[nr] = *(const bf16x8*)&Bs[(wc * 64 + nr * 16 + lr) * 32 + lk8];
#pragma unroll
    for (int mr = 0; mr < 4; mr++)
#pragma unroll
      for (int nr = 0; nr < 4; nr++)
        acc[mr][nr] = __builtin_amdgcn_mfma_f32_16x16x32_bf16(af[mr], bfr[nr],
                                                              acc[mr][nr], 0, 0, 0);
    __syncthreads();
  }

#pragma unroll
  for (int mr = 0; mr < 4; mr++) {
#pragma unroll
    for (int nr = 0; nr < 4; nr++) {
      const int n = bn * 128 + wc * 64 + nr * 16 + lr;
      const float bv = bias[n];
#pragma unroll
      for (int r = 0; r < 4; r++) {
        const int m = bm * 128 + wr * 64 + mr * 16 + lg + r;
        const float v = (acc[mr][nr][r] + bv) * oscale;
        if (mode == 2) {
          ((float*)outp)[(size_t)m * 1024 + n] = v;
        } else {
          const int bb = m >> 11, s = m & (S_ - 1);
          const int hh = n >> 6, dh = n & (DH_ - 1);
          u16* o = (u16*)outp;
          if (mode == 0)
            o[((((size_t)bb * H_ + hh) * S_ + s) << 6) + dh] = f2bf(v);
          else
            o[(((size_t)(bb * H_ + hh) * DH_ + dh) << 11) + s] = f2bf(v);
        }
      }
    }
  }
}

// ---------------- flash attention with random mask (mask is int32 0/1) ----------------
// grid (S/64, H, B), 256 threads = 4 waves, wave w owns q rows [q0+16w, q0+16w+16)
__global__ __launch_bounds__(256) void attn(
    const u16* __restrict__ Q, const u16* __restrict__ K,
    const u16* __restrict__ Vt, const int* __restrict__ maski,
    u16* __restrict__ ctx) {
  __shared__ u16 Kl[64 * 64];
  __shared__ u16 Vl[64 * 64];
  __shared__ u8  Ml[64 * 64];
  __shared__ u16 Pl[4][16 * 64];

  const int tid = threadIdx.x, lane = tid & 63, wid = tid >> 6;
  const int q0 = blockIdx.x * 64;
  const int h = blockIdx.y, b = blockIdx.z;
  const size_t bh = (size_t)b * H_ + h;
  const u16* Qb = Q + (bh * S_ << 6);
  const u16* Kb = K + (bh * S_ << 6);
  const u16* Vb = Vt + (bh * DH_ << 11);
  const int lr = lane & 15, lk8 = (lane >> 4) * 8, lg = (lane >> 4) * 4;

  // Q fragments for this wave's 16 rows (d = 0..63 in two K=32 chunks)
  const bf16x8 qf0 = *(const bf16x8*)(Qb + ((size_t)(q0 + wid * 16 + lr) << 6) + lk8);
  const bf16x8 qf1 = *(const bf16x8*)(Qb + ((size_t)(q0 + wid * 16 + lr) << 6) + 32 + lk8);

  f32x4 zero = {0.f, 0.f, 0.f, 0.f};
  f32x4 acc[4];
#pragma unroll
  for (int i = 0; i < 4; i++) acc[i] = zero;
  float mrow[4] = {-1e30f, -1e30f, -1e30f, -1e30f};
  float lrow[4] = {0.f, 0.f, 0.f, 0.f};

  const int sr = tid >> 3;           // staging row (rows are 64 bf16 = 128B)
  const int scol = (tid & 7) * 8;
  u16* lK = &Kl[tid * 8];
  u16* lV = &Vl[tid * 8];
  const int mrr = tid >> 2, mcc = (tid & 3) << 4;   // mask tile: 64 rows x 64 int32

  for (int kt = 0; kt < S_; kt += 64) {
    gload_lds16(Kb + ((size_t)(kt + sr) << 6) + scol, lK);
    gload_lds16(Kb + ((size_t)(kt + sr + 32) << 6) + scol, lK + 32 * 64);
    gload_lds16(Vb + ((size_t)sr << 11) + kt + scol, lV);
    gload_lds16(Vb + ((size_t)(sr + 32) << 11) + kt + scol, lV + 32 * 64);
    {
      // mask is int32 (harness: integer -> const int*); pack 16 ints -> 16 bytes
      const int* mg = maski + (size_t)(q0 + mrr) * S_ + kt + mcc;
      u32 pk[4];
#pragma unroll
      for (int j = 0; j < 4; j++) {
        int4 mv = *(const int4*)(mg + 4 * j);
        pk[j] = (u32)(mv.x & 1) | ((u32)(mv.y & 1) << 8) |
                ((u32)(mv.z & 1) << 16) | ((u32)(mv.w & 1) << 24);
      }
      *(uint4*)&Ml[mrr * 64 + mcc] = *(const uint4*)pk;
    }
    __syncthreads();

    // scores: 16 q x 64 kv
    f32x4 sc4[4];
#pragma unroll
    for (int nr = 0; nr < 4; nr++) {
      const bf16x8 kf0 = *(const bf16x8*)&Kl[(nr * 16 + lr) * 64 + lk8];
      const bf16x8 kf1 = *(const bf16x8*)&Kl[(nr * 16 + lr) * 64 + 32 + lk8];
      f32x4 z = zero;
      z = __builtin_amdgcn_mfma_f32_16x16x32_bf16(qf0, kf0, z, 0, 0, 0);
      z = __builtin_amdgcn_mfma_f32_16x16x32_bf16(qf1, kf1, z, 0, 0, 0);
      sc4[nr] = z;
    }

    // mask
#pragma unroll
    for (int nr = 0; nr < 4; nr++)
#pragma unroll
      for (int r = 0; r < 4; r++) {
        const int ql = wid * 16 + lg + r;
        if (!Ml[ql * 64 + nr * 16 + lr]) sc4[nr][r] = -1e9f;
      }

    // online softmax (rows live on 16-lane groups)
#pragma unroll
    for (int r = 0; r < 4; r++) {
      float mx = fmaxf(fmaxf(sc4[0][r], sc4[1][r]), fmaxf(sc4[2][r], sc4[3][r]));
      mx = fmaxf(mx, __shfl_xor(mx, 1));
      mx = fmaxf(mx, __shfl_xor(mx, 2));
      mx = fmaxf(mx, __shfl_xor(mx, 4));
      mx = fmaxf(mx, __shfl_xor(mx, 8));
      const float mnew = fmaxf(mrow[r], mx);
      const float alpha = __expf(mrow[r] - mnew);
      mrow[r] = mnew;
      float ps = 0.f;
#pragma unroll
      for (int nr = 0; nr < 4; nr++) {
        const float p = __expf(sc4[nr][r] - mnew);
        sc4[nr][r] = p;
        ps += p;
      }
      ps += __shfl_xor(ps, 1);
      ps += __shfl_xor(ps, 2);
      ps += __shfl_xor(ps, 4);
      ps += __shfl_xor(ps, 8);
      lrow[r] = lrow[r] * alpha + ps;
#pragma unroll
      for (int nc = 0; nc < 4; nc++) acc[nc][r] *= alpha;
    }

    // P -> per-wave LDS (layout fix: A-operand wants row = lane&15)
#pragma unroll
    for (int nr = 0; nr < 4; nr++)
#pragma unroll
      for (int r = 0; r < 4; r++)
        Pl[wid][(lg + r) * 64 + nr * 16 + lr] = f2bf(sc4[nr][r]);

    // PV
#pragma unroll
    for (int ks = 0; ks < 2; ks++) {
      const bf16x8 pf = *(const bf16x8*)&Pl[wid][lr * 64 + ks * 32 + lk8];
#pragma unroll
      for (int nc = 0; nc < 4; nc++) {
        const bf16x8 vf = *(const bf16x8*)&Vl[(nc * 16 + lr) * 64 + ks * 32 + lk8];
        acc[nc] = __builtin_amdgcn_mfma_f32_16x16x32_bf16(pf, vf, acc[nc], 0, 0, 0);
      }
    }
    __syncthreads();
  }

  // epilogue: ctx[b][s][h*DH+d]
#pragma unroll
  for (int nc = 0; nc < 4; nc++)
#pragma unroll
    for (int r = 0; r < 4; r++) {
      const float o = acc[nc][r] / lrow[r];
      const int ql = q0 + wid * 16 + lg + r;
      ctx[((size_t)b * S_ + ql) * D_ + h * DH_ + nc * 16 + lr] = f2bf(o);
    }
}

extern "C" void kernel_launch(void* const* d_in, const int* in_sizes, int n_in,
                              void* d_out, int out_size, void* d_ws, size_t ws_size,
                              hipStream_t stream) {
  const float* X  = (const float*)d_in[0];
  const int* mask = (const int*)d_in[1];
  const float* Wq = (const float*)d_in[2];
  const float* bq = (const float*)d_in[3];
  const float* Wk = (const float*)d_in[4];
  const float* bk = (const float*)d_in[5];
  const float* Wv = (const float*)d_in[6];
  const float* bv = (const float*)d_in[7];
  const float* Wo = (const float*)d_in[8];
  const float* bo = (const float*)d_in[9];

  char* ws = (char*)d_ws;
  const size_t MB = 1024 * 1024;
  u16* xb  = (u16*)(ws);             // 16MB X bf16; reused as ctx after QKV GEMMs
  u16* q   = (u16*)(ws + 16 * MB);   // 16MB
  u16* k   = (u16*)(ws + 32 * MB);   // 16MB
  u16* vt  = (u16*)(ws + 48 * MB);   // 16MB
  u16* wqt = (u16*)(ws + 64 * MB);   // 2MB each
  u16* wkt = (u16*)(ws + 66 * MB);
  u16* wvt = (u16*)(ws + 68 * MB);
  u16* wot = (u16*)(ws + 70 * MB);

  convert_x<<<8192, 256, 0, stream>>>(X, xb);
  transpose_w<<<dim3(16, 16, 4), 256, 0, stream>>>(Wq, Wk, Wv, Wo, wqt, wkt, wvt, wot);

  gemm_bt<<<dim3(64, 8), 256, 0, stream>>>(xb, wqt, bq, q, 0, 0.125f);  // Q (pre-scaled)
  gemm_bt<<<dim3(64, 8), 256, 0, stream>>>(xb, wkt, bk, k, 0, 1.0f);    // K
  gemm_bt<<<dim3(64, 8), 256, 0, stream>>>(xb, wvt, bv, vt, 1, 1.0f);   // V transposed

  attn<<<dim3(S_ / 64, H_, B_), 256, 0, stream>>>(q, k, vt, mask, xb);  // ctx -> xb

  gemm_bt<<<dim3(64, 8), 256, 0, stream>>>(xb, wot, bo, d_out, 2, 1.0f); // out proj
}

// Round 3
// 442.050 us; speedup vs baseline: 1.2785x; 1.2785x over previous
//
#include <hip/hip_runtime.h>

typedef unsigned short u16;
typedef unsigned int   u32;
typedef unsigned long long u64;
typedef unsigned char  u8;
typedef __attribute__((ext_vector_type(8))) short bf16x8;
typedef __attribute__((ext_vector_type(4))) float f32x4;

#define B_  4
#define S_  2048
#define D_  1024
#define H_  16
#define DH_ 64
#define M_  (B_*S_)

__device__ __forceinline__ u16 f2bf(float f) {
  u32 u = __builtin_bit_cast(u32, f);
  u32 r = (u + 0x7FFFu + ((u >> 16) & 1u)) >> 16;   // RNE
  return (u16)r;
}

__device__ __forceinline__ void gload_lds16(const void* g, void* l) {
  __builtin_amdgcn_global_load_lds(
      (const __attribute__((address_space(1))) u32*)g,
      (__attribute__((address_space(3))) u32*)l,
      16, 0, 0);
}

// swizzled LDS fragment read: 16B at (row, colbyte cb), rows are 128B
__device__ __forceinline__ bf16x8 lds_frag(const u16* base, int row, int cb) {
  return *(const bf16x8*)((const char*)base + row * 128 + (cb ^ ((row & 7) << 4)));
}

// ---------------- prep: X f32 -> bf16 ----------------
__global__ __launch_bounds__(256) void convert_x(const float* __restrict__ x,
                                                 u16* __restrict__ xb) {
  const int i = (blockIdx.x * 256 + threadIdx.x) * 4;   // grid 8192 covers 8388608
  float4 v = *(const float4*)(x + i);
  ushort4 o;
  o.x = f2bf(v.x); o.y = f2bf(v.y); o.z = f2bf(v.z); o.w = f2bf(v.w);
  *(ushort4*)(xb + i) = o;
}

// ---------------- prep: W[k][n] f32 -> Wt[n][k] bf16 ----------------
__global__ __launch_bounds__(256) void transpose_w(
    const float* __restrict__ W0, const float* __restrict__ W1,
    const float* __restrict__ W2, const float* __restrict__ W3,
    u16* __restrict__ T0, u16* __restrict__ T1,
    u16* __restrict__ T2, u16* __restrict__ T3) {
  __shared__ float t[64][65];
  const int z = blockIdx.z;
  const float* W = z == 0 ? W0 : z == 1 ? W1 : z == 2 ? W2 : W3;
  u16* T        = z == 0 ? T0 : z == 1 ? T1 : z == 2 ? T2 : T3;
  const int n0 = blockIdx.x * 64, k0 = blockIdx.y * 64;
  const int c = threadIdx.x & 63, r0 = threadIdx.x >> 6;
#pragma unroll
  for (int i = 0; i < 16; i++)
    t[r0 + i * 4][c] = W[(size_t)(k0 + r0 + i * 4) * 1024 + n0 + c];
  __syncthreads();
#pragma unroll
  for (int i = 0; i < 16; i++)
    T[(size_t)(n0 + r0 + i * 4) * 1024 + k0 + c] = f2bf(t[c][r0 + i * 4]);
}

// ---------------- prep: mask int32 -> bitmask u64[2048][32] ----------------
__global__ __launch_bounds__(256) void pack_mask(const int* __restrict__ m,
                                                 u64* __restrict__ mb) {
  const int i = blockIdx.x * 256 + threadIdx.x;     // grid 16384 covers 4M
  const u64 bits = __ballot(m[i] != 0);             // bit l = lane l's predicate
  if ((threadIdx.x & 63) == 0) mb[i >> 6] = bits;
}

// ---------------- prep: fused bias [3072] ----------------
__global__ __launch_bounds__(256) void fuse_bias(const float* __restrict__ bq,
                                                 const float* __restrict__ bk,
                                                 const float* __restrict__ bv,
                                                 float* __restrict__ fb) {
  const int i = blockIdx.x * 256 + threadIdx.x;     // grid 12
  fb[i] = i < 1024 ? bq[i] : (i < 2048 ? bk[i - 1024] : bv[i - 2048]);
}

// ---------------- GEMM: C[8192,N] = A[8192,1024] @ Bt[N,1024]^T + bias --------
// mode 3: fused QKV (N=3072): bf16 out into q/k/vt buffers (outp = q base)
// mode 2: f32 out, row-major [m][1024] (final projection)
__global__ __launch_bounds__(256) void gemm_bt(
    const u16* __restrict__ A, const u16* __restrict__ Bw,
    const float* __restrict__ bias, void* __restrict__ outp, int mode) {
  __shared__ u16 As[128 * 32];
  __shared__ u16 Bs[128 * 32];
  const int tid = threadIdx.x;
  const int lane = tid & 63, wid = tid >> 6;
  const int wr = wid >> 1, wc = wid & 1;
  const int bm = blockIdx.x, bn = blockIdx.y;
  const int lr = lane & 15, lk8 = (lane >> 4) * 8, lg = (lane >> 4) * 4;

  f32x4 zero = {0.f, 0.f, 0.f, 0.f};
  f32x4 acc[4][4];
#pragma unroll
  for (int i = 0; i < 4; i++)
#pragma unroll
    for (int j = 0; j < 4; j++) acc[i][j] = zero;

  const int r0 = tid >> 2;            // tile row (of 128), rows are 32 bf16 = 64B
  const int c0 = (tid & 3) * 8;       // elem col within row
  const u16* gA = A + ((size_t)(bm * 128 + r0) << 10) + c0;
  const u16* gB = Bw + ((size_t)(bn * 128 + r0) << 10) + c0;
  u16* lA = &As[tid * 8];
  u16* lB = &Bs[tid * 8];

  for (int kt = 0; kt < 1024; kt += 32) {
    gload_lds16(gA + kt, lA);
    gload_lds16(gA + kt + (64 << 10), lA + 64 * 32);
    gload_lds16(gB + kt, lB);
    gload_lds16(gB + kt + (64 << 10), lB + 64 * 32);
    __syncthreads();

    bf16x8 af[4], bfr[4];
#pragma unroll
    for (int mr = 0; mr < 4; mr++)
      af[mr] = *(const bf16x8*)&As[(wr * 64 + mr * 16 + lr) * 32 + lk8];
#pragma unroll
    for (int nr = 0; nr < 4; nr++)
      bfr[nr] = *(const bf16x8*)&Bs[(wc * 64 + nr * 16 + lr) * 32 + lk8];
#pragma unroll
    for (int mr = 0; mr < 4; mr++)
#pragma unroll
      for (int nr = 0; nr < 4; nr++)
        acc[mr][nr] = __builtin_amdgcn_mfma_f32_16x16x32_bf16(af[mr], bfr[nr],
                                                              acc[mr][nr], 0, 0, 0);
    __syncthreads();
  }

#pragma unroll
  for (int mr = 0; mr < 4; mr++) {
#pragma unroll
    for (int nr = 0; nr < 4; nr++) {
      const int n = bn * 128 + wc * 64 + nr * 16 + lr;
      const float bv = bias[n];
#pragma unroll
      for (int r = 0; r < 4; r++) {
        const int m = bm * 128 + wr * 64 + mr * 16 + lg + r;
        float v = acc[mr][nr][r] + bv;
        if (mode == 2) {
          ((float*)outp)[(size_t)m * 1024 + n] = v;
        } else {
          const int which = n >> 10, col = n & 1023;
          const int bb = m >> 11, s = m & (S_ - 1);
          const int hh = col >> 6, dh = col & (DH_ - 1);
          if (which == 0) v *= 0.125f;   // Q pre-scaled by 1/sqrt(DH)
          u16* o = (u16*)outp + ((size_t)which << 23);   // +16MB per tensor
          if (which <= 1)
            o[((((size_t)bb * H_ + hh) * S_ + s) << 6) + dh] = f2bf(v);     // Q,K
          else
            o[(((size_t)(bb * H_ + hh) * DH_ + dh) << 11) + s] = f2bf(v);   // V^T
        }
      }
    }
  }
}

// ---------------- flash attention, bitmask, swizzled LDS ----------------
// grid (S/64, H, B), 256 threads = 4 waves, wave w owns q rows [q0+16w, q0+16w+16)
__global__ __launch_bounds__(256) void attn(
    const u16* __restrict__ Q, const u16* __restrict__ K,
    const u16* __restrict__ Vt, const u64* __restrict__ mb,
    u16* __restrict__ ctx) {
  __shared__ u16 Kl[64 * 64];
  __shared__ u16 Vl[64 * 64];
  __shared__ u16 Pl[4][16 * 64];

  const int tid = threadIdx.x, lane = tid & 63, wid = tid >> 6;
  const int q0 = blockIdx.x * 64;
  const int h = blockIdx.y, b = blockIdx.z;
  const size_t bh = (size_t)b * H_ + h;
  const u16* Qb = Q + (bh * S_ << 6);
  const u16* Kb = K + (bh * S_ << 6);
  const u16* Vb = Vt + (bh * DH_ << 11);
  const int lr = lane & 15, g = lane >> 4, lk8 = g * 8, lg = g * 4;

  const bf16x8 qf0 = *(const bf16x8*)(Qb + ((size_t)(q0 + wid * 16 + lr) << 6) + lk8);
  const bf16x8 qf1 = *(const bf16x8*)(Qb + ((size_t)(q0 + wid * 16 + lr) << 6) + 32 + lk8);

  f32x4 zero = {0.f, 0.f, 0.f, 0.f};
  f32x4 acc[4];
#pragma unroll
  for (int i = 0; i < 4; i++) acc[i] = zero;
  float mrow[4] = {-1e30f, -1e30f, -1e30f, -1e30f};
  float lrow[4] = {0.f, 0.f, 0.f, 0.f};

  // staging: thread t -> LDS bytes t*16 (row sr = t>>3, col (t&7)*16);
  // source column pre-swizzled so swizzled reads see the right data (rule #21)
  const int sr = tid >> 3;
  const int scz = ((((tid & 7) * 16) ^ ((sr & 7) << 4)) >> 1);   // u16 units
  u16* lK = &Kl[tid * 8];
  u16* lV = &Vl[tid * 8];
  const int qrow_base = q0 + wid * 16 + lg;

  for (int kt = 0; kt < S_; kt += 64) {
    // mask bit-words (issued early; same addr across 16-lane group -> broadcast)
    u64 mw[4];
#pragma unroll
    for (int r = 0; r < 4; r++)
      mw[r] = mb[(size_t)(qrow_base + r) * 32 + (kt >> 6)];

    gload_lds16(Kb + ((size_t)(kt + sr) << 6) + scz, lK);
    gload_lds16(Kb + ((size_t)(kt + sr + 32) << 6) + scz, lK + 32 * 64);
    gload_lds16(Vb + ((size_t)sr << 11) + kt + scz, lV);
    gload_lds16(Vb + ((size_t)(sr + 32) << 11) + kt + scz, lV + 32 * 64);
    __syncthreads();

    // scores: 16 q x 64 kv
    f32x4 sc4[4];
    __builtin_amdgcn_s_setprio(1);
#pragma unroll
    for (int nr = 0; nr < 4; nr++) {
      const int row = nr * 16 + lr;
      const bf16x8 kf0 = lds_frag(Kl, row, lk8 * 2);
      const bf16x8 kf1 = lds_frag(Kl, row, 64 + lk8 * 2);
      f32x4 z = zero;
      z = __builtin_amdgcn_mfma_f32_16x16x32_bf16(qf0, kf0, z, 0, 0, 0);
      z = __builtin_amdgcn_mfma_f32_16x16x32_bf16(qf1, kf1, z, 0, 0, 0);
      sc4[nr] = z;
    }
    __builtin_amdgcn_s_setprio(0);

    // mask from bits
#pragma unroll
    for (int nr = 0; nr < 4; nr++)
#pragma unroll
      for (int r = 0; r < 4; r++)
        if (!((mw[r] >> (nr * 16 + lr)) & 1ull)) sc4[nr][r] = -1e9f;

    // online softmax (rows live on 16-lane groups)
#pragma unroll
    for (int r = 0; r < 4; r++) {
      float mx = fmaxf(fmaxf(sc4[0][r], sc4[1][r]), fmaxf(sc4[2][r], sc4[3][r]));
      mx = fmaxf(mx, __shfl_xor(mx, 1));
      mx = fmaxf(mx, __shfl_xor(mx, 2));
      mx = fmaxf(mx, __shfl_xor(mx, 4));
      mx = fmaxf(mx, __shfl_xor(mx, 8));
      const float mnew = fmaxf(mrow[r], mx);
      const float alpha = __expf(mrow[r] - mnew);
      mrow[r] = mnew;
      float ps = 0.f;
#pragma unroll
      for (int nr = 0; nr < 4; nr++) {
        const float p = __expf(sc4[nr][r] - mnew);
        sc4[nr][r] = p;
        ps += p;
      }
      ps += __shfl_xor(ps, 1);
      ps += __shfl_xor(ps, 2);
      ps += __shfl_xor(ps, 4);
      ps += __shfl_xor(ps, 8);
      lrow[r] = lrow[r] * alpha + ps;
#pragma unroll
      for (int nc = 0; nc < 4; nc++) acc[nc][r] *= alpha;
    }

    // P -> per-wave LDS (swizzled scatter; reads below use lds_frag)
    {
      char* pw = (char*)Pl[wid];
#pragma unroll
      for (int nr = 0; nr < 4; nr++)
#pragma unroll
        for (int r = 0; r < 4; r++) {
          const int qr = lg + r, cb = (nr * 16 + lr) * 2;
          *(u16*)(pw + qr * 128 + (cb ^ ((qr & 7) << 4))) = f2bf(sc4[nr][r]);
        }
    }

    // PV
#pragma unroll
    for (int ks = 0; ks < 2; ks++) {
      const bf16x8 pf = lds_frag(Pl[wid], lr, ks * 64 + lk8 * 2);
      __builtin_amdgcn_s_setprio(1);
#pragma unroll
      for (int nc = 0; nc < 4; nc++) {
        const bf16x8 vf = lds_frag(Vl, nc * 16 + lr, ks * 64 + lk8 * 2);
        acc[nc] = __builtin_amdgcn_mfma_f32_16x16x32_bf16(pf, vf, acc[nc], 0, 0, 0);
      }
      __builtin_amdgcn_s_setprio(0);
    }
    __syncthreads();
  }

  // epilogue: ctx[b][s][h*DH+d]
#pragma unroll
  for (int nc = 0; nc < 4; nc++)
#pragma unroll
    for (int r = 0; r < 4; r++) {
      const float o = acc[nc][r] / lrow[r];
      const int ql = q0 + wid * 16 + lg + r;
      ctx[((size_t)b * S_ + ql) * D_ + h * DH_ + nc * 16 + lr] = f2bf(o);
    }
}

extern "C" void kernel_launch(void* const* d_in, const int* in_sizes, int n_in,
                              void* d_out, int out_size, void* d_ws, size_t ws_size,
                              hipStream_t stream) {
  const float* X  = (const float*)d_in[0];
  const int* mask = (const int*)d_in[1];
  const float* Wq = (const float*)d_in[2];
  const float* bq = (const float*)d_in[3];
  const float* Wk = (const float*)d_in[4];
  const float* bk = (const float*)d_in[5];
  const float* Wv = (const float*)d_in[6];
  const float* bv = (const float*)d_in[7];
  const float* Wo = (const float*)d_in[8];
  const float* bo = (const float*)d_in[9];

  char* ws = (char*)d_ws;
  const size_t MB = 1024 * 1024;
  u16* xb  = (u16*)(ws);             // 16MB X bf16; reused as ctx after attn
  u16* q   = (u16*)(ws + 16 * MB);   // 16MB (k, vt follow at +16MB each)
  u16* wqt = (u16*)(ws + 64 * MB);   // 3x2MB contiguous = fused [3072][1024]
  u16* wkt = (u16*)(ws + 66 * MB);
  u16* wvt = (u16*)(ws + 68 * MB);
  u16* wot = (u16*)(ws + 70 * MB);
  u64* mbb = (u64*)(ws + 72 * MB);   // 512KB bitmask
  float* fb = (float*)(ws + 72 * MB + 512 * 1024);  // 12KB fused bias

  convert_x<<<8192, 256, 0, stream>>>(X, xb);
  transpose_w<<<dim3(16, 16, 4), 256, 0, stream>>>(Wq, Wk, Wv, Wo, wqt, wkt, wvt, wot);
  pack_mask<<<16384, 256, 0, stream>>>(mask, mbb);
  fuse_bias<<<12, 256, 0, stream>>>(bq, bk, bv, fb);

  gemm_bt<<<dim3(64, 24), 256, 0, stream>>>(xb, wqt, fb, q, 3);      // fused QKV

  u16* k  = q + (1u << 23);
  u16* vt = q + (2u << 23);
  attn<<<dim3(S_ / 64, H_, B_), 256, 0, stream>>>(q, k, vt, mbb, xb); // ctx -> xb

  gemm_bt<<<dim3(64, 8), 256, 0, stream>>>(xb, wot, bo, d_out, 2);   // out proj
}

// Round 4
// 363.842 us; speedup vs baseline: 1.5533x; 1.2150x over previous
//
#include <hip/hip_runtime.h>

typedef unsigned short u16;
typedef unsigned int   u32;
typedef unsigned long long u64;
typedef unsigned char  u8;
typedef __attribute__((ext_vector_type(8))) short bf16x8;
typedef __attribute__((ext_vector_type(4))) float f32x4;

#define B_  4
#define S_  2048
#define D_  1024
#define H_  16
#define DH_ 64

#define MFMA16 __builtin_amdgcn_mfma_f32_16x16x32_bf16

__device__ __forceinline__ u16 f2bf(float f) {
  u32 u = __builtin_bit_cast(u32, f);
  u32 r = (u + 0x7FFFu + ((u >> 16) & 1u)) >> 16;   // RNE
  return (u16)r;
}

__device__ __forceinline__ u32 cvt_pk_bf16(float lo, float hi) {
  u32 r;
  asm("v_cvt_pk_bf16_f32 %0, %1, %2" : "=v"(r) : "v"(lo), "v"(hi));
  return r;
}

__device__ __forceinline__ float exp2_fast(float x) {   // 2^x
  float r;
  asm("v_exp_f32 %0, %1" : "=v"(r) : "v"(x));
  return r;
}

__device__ __forceinline__ void gload_lds16(const void* g, void* l) {
  __builtin_amdgcn_global_load_lds(
      (const __attribute__((address_space(1))) u32*)g,
      (__attribute__((address_space(3))) u32*)l,
      16, 0, 0);
}

// swizzled LDS fragment read: 16B at (row, colbyte cb), rows are 128B
__device__ __forceinline__ bf16x8 lds_frag(const u16* base, int row, int cb) {
  return *(const bf16x8*)((const char*)base + row * 128 + (cb ^ ((row & 7) << 4)));
}

// ---------------- prep: X->bf16 | mask->bitmask | bias fuse ----------------
__global__ __launch_bounds__(256) void prep(
    const float* __restrict__ x, u16* __restrict__ xb,
    const int* __restrict__ m, u64* __restrict__ mbw,
    const float* __restrict__ bq, const float* __restrict__ bk,
    const float* __restrict__ bv, float* __restrict__ fb) {
  const int blk = blockIdx.x;
  if (blk < 8192) {                       // X f32 -> bf16 (8.39M elems)
    const int i = (blk * 256 + threadIdx.x) * 4;
    float4 v = *(const float4*)(x + i);
    ushort4 o;
    o.x = f2bf(v.x); o.y = f2bf(v.y); o.z = f2bf(v.z); o.w = f2bf(v.w);
    *(ushort4*)(xb + i) = o;
  } else if (blk < 8192 + 2048) {         // mask int32 -> u64 bitmask
    const int base = (blk - 8192) * 2048;
#pragma unroll
    for (int it = 0; it < 8; it++) {
      const int i = base + it * 256 + threadIdx.x;
      const u64 bits = __ballot(m[i] != 0);
      if ((threadIdx.x & 63) == 0) mbw[i >> 6] = bits;
    }
  } else {                                // fused bias [3072]
    const int i = (blk - 10240) * 256 + threadIdx.x;
    fb[i] = i < 1024 ? bq[i] : (i < 2048 ? bk[i - 1024] : bv[i - 2048]);
  }
}

// ---------------- prep: W[k][n] f32 -> Wt[n][k] bf16 ----------------
__global__ __launch_bounds__(256) void transpose_w(
    const float* __restrict__ W0, const float* __restrict__ W1,
    const float* __restrict__ W2, const float* __restrict__ W3,
    u16* __restrict__ T0, u16* __restrict__ T1,
    u16* __restrict__ T2, u16* __restrict__ T3) {
  __shared__ float t[64][65];
  const int z = blockIdx.z;
  const float* W = z == 0 ? W0 : z == 1 ? W1 : z == 2 ? W2 : W3;
  u16* T        = z == 0 ? T0 : z == 1 ? T1 : z == 2 ? T2 : T3;
  const int n0 = blockIdx.x * 64, k0 = blockIdx.y * 64;
  const int c = threadIdx.x & 63, r0 = threadIdx.x >> 6;
#pragma unroll
  for (int i = 0; i < 16; i++)
    t[r0 + i * 4][c] = W[(size_t)(k0 + r0 + i * 4) * 1024 + n0 + c];
  __syncthreads();
#pragma unroll
  for (int i = 0; i < 16; i++)
    T[(size_t)(n0 + r0 + i * 4) * 1024 + k0 + c] = f2bf(t[c][r0 + i * 4]);
}

// ---------------- GEMM: C[8192,N] = A[8192,1024] @ Bt[N,1024]^T + bias --------
// mode 3: fused QKV (N=3072): bf16 out into q/k/vt buffers (outp = q base)
// mode 2: f32 out, row-major [m][1024] (final projection)
__global__ __launch_bounds__(256) void gemm_bt(
    const u16* __restrict__ A, const u16* __restrict__ Bw,
    const float* __restrict__ bias, void* __restrict__ outp, int mode) {
  __shared__ u16 As[2][128 * 32];
  __shared__ u16 Bs[2][128 * 32];
  const int tid = threadIdx.x;
  const int lane = tid & 63, wid = tid >> 6;
  const int wr = wid >> 1, wc = wid & 1;
  const int bm = blockIdx.x, bn = blockIdx.y;
  const int lr = lane & 15, lk8 = (lane >> 4) * 8, lg = (lane >> 4) * 4;

  f32x4 acc[4][4];
#pragma unroll
  for (int i = 0; i < 4; i++)
#pragma unroll
    for (int j = 0; j < 4; j++) acc[i][j] = (f32x4){0.f, 0.f, 0.f, 0.f};

  const int r0 = tid >> 2;            // tile row (of 128), rows are 32 bf16 = 64B
  const int c0 = (tid & 3) * 8;       // elem col within row
  const u16* gA = A + ((size_t)(bm * 128 + r0) << 10) + c0;
  const u16* gB = Bw + ((size_t)(bn * 128 + r0) << 10) + c0;

#define GSTAGE(ki, bf) do {                                        \
    const int kt_ = (ki) * 32;                                     \
    gload_lds16(gA + kt_, &As[bf][tid * 8]);                       \
    gload_lds16(gA + kt_ + (64 << 10), &As[bf][tid * 8 + 64 * 32]);\
    gload_lds16(gB + kt_, &Bs[bf][tid * 8]);                       \
    gload_lds16(gB + kt_ + (64 << 10), &Bs[bf][tid * 8 + 64 * 32]);\
  } while (0)

  GSTAGE(0, 0);
  __syncthreads();

  for (int ki = 0; ki < 32; ki++) {
    const int cur = ki & 1;
    if (ki + 1 < 32) GSTAGE(ki + 1, cur ^ 1);

    bf16x8 af[4], bfr[4];
#pragma unroll
    for (int mr = 0; mr < 4; mr++)
      af[mr] = *(const bf16x8*)&As[cur][(wr * 64 + mr * 16 + lr) * 32 + lk8];
#pragma unroll
    for (int nr = 0; nr < 4; nr++)
      bfr[nr] = *(const bf16x8*)&Bs[cur][(wc * 64 + nr * 16 + lr) * 32 + lk8];
    __builtin_amdgcn_s_setprio(1);
#pragma unroll
    for (int mr = 0; mr < 4; mr++)
#pragma unroll
      for (int nr = 0; nr < 4; nr++)
        acc[mr][nr] = MFMA16(af[mr], bfr[nr], acc[mr][nr], 0, 0, 0);
    __builtin_amdgcn_s_setprio(0);
    __syncthreads();
  }

#pragma unroll
  for (int mr = 0; mr < 4; mr++) {
#pragma unroll
    for (int nr = 0; nr < 4; nr++) {
      const int n = bn * 128 + wc * 64 + nr * 16 + lr;
      const float bv = bias[n];
#pragma unroll
      for (int r = 0; r < 4; r++) {
        const int m = bm * 128 + wr * 64 + mr * 16 + lg + r;
        float v = acc[mr][nr][r] + bv;
        if (mode == 2) {
          ((float*)outp)[(size_t)m * 1024 + n] = v;
        } else {
          const int which = n >> 10, col = n & 1023;
          const int bb = m >> 11, s = m & (S_ - 1);
          const int hh = col >> 6, dh = col & (DH_ - 1);
          if (which == 0) v *= 0.180336880f;   // (1/sqrt(64)) * log2(e)
          u16* o = (u16*)outp + ((size_t)which << 23);   // +16MB per tensor
          if (which <= 1)
            o[((((size_t)bb * H_ + hh) * S_ + s) << 6) + dh] = f2bf(v);     // Q,K
          else
            o[(((size_t)(bb * H_ + hh) * DH_ + dh) << 11) + s] = f2bf(v);   // V^T
        }
      }
    }
  }
}

// ---------------- flash attention: swapped QK^T, lane-local softmax ----------------
// grid (S/64, H, B), 256 threads = 4 waves, wave w owns q rows [q0+16w, q0+16w+16)
// Per lane: q-hat = lane&15 (softmax state), slots hold q = g*4+reg for acc.
__global__ __launch_bounds__(256) void attn(
    const u16* __restrict__ Q, const u16* __restrict__ K,
    const u16* __restrict__ Vt, const u64* __restrict__ mb,
    u16* __restrict__ ctx) {
  __shared__ u16 Kl[2][64 * 64];
  __shared__ u16 Vl[2][64 * 64];
  __shared__ u16 Pl[4][16 * 64];

  const int tid = threadIdx.x, lane = tid & 63, wid = tid >> 6;
  const int q0 = blockIdx.x * 64;
  const int h = blockIdx.y, b = blockIdx.z;
  const size_t bh = (size_t)b * H_ + h;
  const u16* Qb = Q + (bh * S_ << 6);
  const u16* Kb = K + (bh * S_ << 6);
  const u16* Vb = Vt + (bh * DH_ << 11);
  const int qh = lane & 15, g = lane >> 4, lk8 = g * 8;
  const int qrow = q0 + wid * 16 + qh;      // this lane's softmax row

  // Q fragments (Y-operand rows = q)
  const bf16x8 qf0 = *(const bf16x8*)(Qb + ((size_t)qrow << 6) + lk8);
  const bf16x8 qf1 = *(const bf16x8*)(Qb + ((size_t)qrow << 6) + 32 + lk8);

  f32x4 acc[4];                              // acc[nc][r]: O[q=g*4+r][d=nc*16+qh]
#pragma unroll
  for (int i = 0; i < 4; i++) acc[i] = (f32x4){0.f, 0.f, 0.f, 0.f};
  float mrun = -1e30f, lrun = 0.f;           // log2-domain running max / sum

  const int sr = tid >> 3;                   // staging row, rows are 128B
  const int scz = ((((tid & 7) * 16) ^ ((sr & 7) << 4)) >> 1);   // pre-swizzled col (u16)

#define ASTAGE(t, bf) do {                                                  \
    const int kt_ = (t) * 64;                                               \
    gload_lds16(Kb + ((size_t)(kt_ + sr) << 6) + scz, &Kl[bf][tid * 8]);    \
    gload_lds16(Kb + ((size_t)(kt_ + sr + 32) << 6) + scz,                  \
                &Kl[bf][tid * 8 + 32 * 64]);                                \
    gload_lds16(Vb + ((size_t)sr << 11) + kt_ + scz, &Vl[bf][tid * 8]);     \
    gload_lds16(Vb + ((size_t)(sr + 32) << 11) + kt_ + scz,                 \
                &Vl[bf][tid * 8 + 32 * 64]);                                \
  } while (0)

  ASTAGE(0, 0);
  __syncthreads();

  for (int t = 0; t < S_ / 64; t++) {
    const int cur = t & 1;
    if (t + 1 < S_ / 64) ASTAGE(t + 1, cur ^ 1);
    const u64 mw = mb[((size_t)qrow << 5) + t];   // mask bits for this lane's q-row

    // QK^T swapped: sc[nr][r] = S[k = nr*16 + g*4 + r][q = qh]
    f32x4 sc[4];
    __builtin_amdgcn_s_setprio(1);
#pragma unroll
    for (int nr = 0; nr < 4; nr++) {
      const int row = nr * 16 + qh;
      const bf16x8 kf0 = lds_frag(Kl[cur], row, lk8 * 2);
      const bf16x8 kf1 = lds_frag(Kl[cur], row, 64 + lk8 * 2);
      f32x4 z = (f32x4){0.f, 0.f, 0.f, 0.f};
      z = MFMA16(kf0, qf0, z, 0, 0, 0);
      z = MFMA16(kf1, qf1, z, 0, 0, 0);
      sc[nr] = z;
    }
    __builtin_amdgcn_s_setprio(0);

    // mask: bit (nr*16 + g*4 + r) of mw
    const u64 mwg = mw >> (g * 4);
    const u32 mlo = (u32)mwg, mhi = (u32)(mwg >> 32);
#pragma unroll
    for (int nr = 0; nr < 4; nr++) {
      const u32 wsel = (nr & 2) ? mhi : mlo;
      const int sh = (nr & 1) * 16;
#pragma unroll
      for (int r = 0; r < 4; r++)
        if (!((wsel >> (sh + r)) & 1u)) sc[nr][r] = -1e9f;
    }

    // tile max for row qh: in-lane 16 + cross-lane (x16, x32)
    float tmax = sc[0][0];
#pragma unroll
    for (int nr = 0; nr < 4; nr++)
#pragma unroll
      for (int r = 0; r < 4; r++) tmax = fmaxf(tmax, sc[nr][r]);
    tmax = fmaxf(tmax, __shfl_xor(tmax, 16));
    tmax = fmaxf(tmax, __shfl_xor(tmax, 32));

    // defer-max: rescale only when the max grew past THR=8 (P bounded by 2^8)
    if (!__all(tmax <= mrun + 8.0f)) {
      const float mnew = fmaxf(mrun, tmax);
      const float alpha = exp2_fast(mrun - mnew);
      lrun *= alpha;
      mrun = mnew;
#pragma unroll
      for (int r = 0; r < 4; r++) {
        const float as = __shfl(alpha, g * 4 + r);   // alpha for slot-row q=g*4+r
        acc[0][r] *= as; acc[1][r] *= as; acc[2][r] *= as; acc[3][r] *= as;
      }
    }

    // P = 2^(s - m), row sum, pack to bf16 pairs
    float ts = 0.f;
    u32 w[8];
#pragma unroll
    for (int nr = 0; nr < 4; nr++) {
      float p0 = exp2_fast(sc[nr][0] - mrun);
      float p1 = exp2_fast(sc[nr][1] - mrun);
      float p2 = exp2_fast(sc[nr][2] - mrun);
      float p3 = exp2_fast(sc[nr][3] - mrun);
      ts += (p0 + p1) + (p2 + p3);
      w[nr * 2]     = cvt_pk_bf16(p0, p1);
      w[nr * 2 + 1] = cvt_pk_bf16(p2, p3);
    }
    ts += __shfl_xor(ts, 16);
    ts += __shfl_xor(ts, 32);
    lrun += ts;

    // P -> per-wave LDS (swizzled b32 writes; 2-way bank alias = free)
    {
      char* pw = (char*)Pl[wid] + qh * 128;
      const int sw = (qh & 7) << 4;
#pragma unroll
      for (int nr = 0; nr < 4; nr++) {
        *(u32*)(pw + ((g * 8 + nr * 32) ^ sw))     = w[nr * 2];
        *(u32*)(pw + ((g * 8 + 4 + nr * 32) ^ sw)) = w[nr * 2 + 1];
      }
    }

    // PV: acc[nc] += P[q][k] * V^T[d][k]
#pragma unroll
    for (int ks = 0; ks < 2; ks++) {
      const bf16x8 pf = lds_frag(Pl[wid], qh, ks * 64 + lk8 * 2);
      __builtin_amdgcn_s_setprio(1);
#pragma unroll
      for (int nc = 0; nc < 4; nc++) {
        const bf16x8 vf = lds_frag(Vl[cur], nc * 16 + qh, ks * 64 + lk8 * 2);
        acc[nc] = MFMA16(pf, vf, acc[nc], 0, 0, 0);
      }
      __builtin_amdgcn_s_setprio(0);
    }
    __syncthreads();
  }

  // epilogue: ctx[b][s][h*DH+d], d = nc*16+qh, q = g*4+r
  float linv[4];
#pragma unroll
  for (int r = 0; r < 4; r++) linv[r] = 1.0f / __shfl(lrun, g * 4 + r);
#pragma unroll
  for (int nc = 0; nc < 4; nc++)
#pragma unroll
    for (int r = 0; r < 4; r++) {
      const float o = acc[nc][r] * linv[r];
      const int ql = q0 + wid * 16 + g * 4 + r;
      ctx[((size_t)b * S_ + ql) * D_ + h * DH_ + nc * 16 + qh] = f2bf(o);
    }
}

extern "C" void kernel_launch(void* const* d_in, const int* in_sizes, int n_in,
                              void* d_out, int out_size, void* d_ws, size_t ws_size,
                              hipStream_t stream) {
  const float* X  = (const float*)d_in[0];
  const int* mask = (const int*)d_in[1];
  const float* Wq = (const float*)d_in[2];
  const float* bq = (const float*)d_in[3];
  const float* Wk = (const float*)d_in[4];
  const float* bk = (const float*)d_in[5];
  const float* Wv = (const float*)d_in[6];
  const float* bv = (const float*)d_in[7];
  const float* Wo = (const float*)d_in[8];
  const float* bo = (const float*)d_in[9];

  char* ws = (char*)d_ws;
  const size_t MB = 1024 * 1024;
  u16* xb  = (u16*)(ws);             // 16MB X bf16; reused as ctx after attn
  u16* q   = (u16*)(ws + 16 * MB);   // 16MB (k, vt follow at +16MB each)
  u16* wqt = (u16*)(ws + 64 * MB);   // 3x2MB contiguous = fused [3072][1024]
  u16* wkt = (u16*)(ws + 66 * MB);
  u16* wvt = (u16*)(ws + 68 * MB);
  u16* wot = (u16*)(ws + 70 * MB);
  u64* mbb = (u64*)(ws + 72 * MB);   // 512KB bitmask
  float* fb = (float*)(ws + 72 * MB + 512 * 1024);  // 12KB fused bias

  prep<<<10252, 256, 0, stream>>>(X, xb, mask, mbb, bq, bk, bv, fb);
  transpose_w<<<dim3(16, 16, 4), 256, 0, stream>>>(Wq, Wk, Wv, Wo, wqt, wkt, wvt, wot);

  gemm_bt<<<dim3(64, 24), 256, 0, stream>>>(xb, wqt, fb, q, 3);      // fused QKV

  u16* k  = q + (1u << 23);
  u16* vt = q + (2u << 23);
  attn<<<dim3(S_ / 64, H_, B_), 256, 0, stream>>>(q, k, vt, mbb, xb); // ctx -> xb

  gemm_bt<<<dim3(64, 8), 256, 0, stream>>>(xb, wot, bo, d_out, 2);   // out proj
}